// Round 1
// baseline (487.358 us; speedup 1.0000x reference)
//
#include <hip/hip_runtime.h>
#include <hip/hip_bf16.h>

#define N_ROWS 4096
#define K_IN   8192
#define F_DIM  2048
#define GAMMA  (1.0f / 2048.0f)

typedef unsigned short u16;
typedef unsigned int   u32;
typedef __attribute__((ext_vector_type(8))) __bf16 bf16x8;
typedef __attribute__((ext_vector_type(4))) float  f32x4;

__device__ __forceinline__ u16 f2bf(float f) {
  u32 u = __float_as_uint(f);
  u = (u + 0x7FFFu + ((u >> 16) & 1u)) >> 16;
  return (u16)u;
}
__device__ __forceinline__ float bf2f(u16 h) {
  return __uint_as_float(((u32)h) << 16);
}

__device__ __forceinline__ void async16(const void* g, void* l) {
  __builtin_amdgcn_global_load_lds(
      (const __attribute__((address_space(1))) void*)g,
      (__attribute__((address_space(3))) void*)l, 16, 0, 0);
}

// ---------------- conversion kernels ----------------

__global__ void convert_xs(const float4* __restrict__ in, ushort4* __restrict__ out, int n4) {
  int idx = blockIdx.x * blockDim.x + threadIdx.x;
  int stride = gridDim.x * blockDim.x;
  for (int i = idx; i < n4; i += stride) {
    float4 v = in[i];
    ushort4 o;
    o.x = f2bf(v.x); o.y = f2bf(v.y); o.z = f2bf(v.z); o.w = f2bf(v.w);
    out[i] = o;
  }
}

// W [K_IN, F_DIM] fp32 -> Wt [F_DIM, K_IN] bf16
__global__ void transpose_w(const float* __restrict__ W, u16* __restrict__ Wt) {
  __shared__ float tile[32][33];
  int bx = blockIdx.x;           // over F_DIM/32
  int by = blockIdx.y;           // over K_IN/32
  int tx = threadIdx.x, ty = threadIdx.y;   // (32, 8)
  int col = bx * 32 + tx;        // F index
  int rowbase = by * 32;         // K index base
  for (int i = ty; i < 32; i += 8)
    tile[i][tx] = W[(size_t)(rowbase + i) * F_DIM + col];
  __syncthreads();
  for (int i = ty; i < 32; i += 8)
    Wt[(size_t)(bx * 32 + i) * K_IN + rowbase + tx] = f2bf(tile[tx][i]);
}

// beta[i] = alpha[i] * (2*y[i]-1); out[0] = -sum(alpha)
__global__ void prep(const float* __restrict__ alphas, const int* __restrict__ ys,
                     float* __restrict__ beta, float* __restrict__ out) {
  __shared__ float red[1024];
  int t = threadIdx.x;
  float s = 0.f;
  for (int i = t; i < N_ROWS; i += 1024) {
    float a = alphas[i];
    beta[i] = a * (float)(2 * ys[i] - 1);
    s += a;
  }
  red[t] = s;
  __syncthreads();
  for (int off = 512; off; off >>= 1) {
    if (t < off) red[t] += red[t + off];
    __syncthreads();
  }
  if (t == 0) out[0] = -red[0];
}

// sq[i] = sum_f X_bf[i][f]^2
__global__ void row_sq(const u16* __restrict__ X, float* __restrict__ sq) {
  int wave = threadIdx.x >> 6, lane = threadIdx.x & 63;
  int row = blockIdx.x * 4 + wave;
  const u16* xr = X + (size_t)row * F_DIM;
  float s = 0.f;
  for (int c = lane * 8; c < F_DIM; c += 512) {
    uint4 v = *(const uint4*)(xr + c);
    u32 a[4] = {v.x, v.y, v.z, v.w};
#pragma unroll
    for (int p = 0; p < 4; ++p) {
      float lo = __uint_as_float(a[p] << 16);
      float hi = __uint_as_float(a[p] & 0xffff0000u);
      s += lo * lo + hi * hi;
    }
  }
#pragma unroll
  for (int off = 32; off; off >>= 1) s += __shfl_down(s, off);
  if (lane == 0) sq[row] = s;
}

// ---------------- GEMM core (128x128 tile, BK=64, xor-8 swizzled LDS) ----------------

template <int K>
__device__ __forceinline__ void gemm_tile(const u16* __restrict__ A, const u16* __restrict__ Bt,
                                          int m0, int n0, u16* sA, u16* sB, int tid,
                                          f32x4 acc[4][4]) {
  const int lane = tid & 63;
  const int q = lane >> 4;
  const int r = lane & 15;
  const int wave = tid >> 6;
  const int wm = (wave >> 1) << 6;
  const int wn = (wave & 1) << 6;

  const f32x4 zero = {0.f, 0.f, 0.f, 0.f};
#pragma unroll
  for (int mt = 0; mt < 4; ++mt)
#pragma unroll
    for (int nt = 0; nt < 4; ++nt) acc[mt][nt] = zero;

  int rowS[4], colS[4], offS[4];
#pragma unroll
  for (int j = 0; j < 4; ++j) {
    int o = tid * 16 + j * 4096;   // byte offset inside 16KB tile
    int row = o >> 7;              // 128B per LDS row (64 bf16)
    int cb = (o >> 4) & 7;         // 16B col-block within row
    rowS[j] = row;
    colS[j] = ((cb ^ (row & 7)) << 3);  // global element col (xor swizzle)
    offS[j] = o;
  }

  for (int k0 = 0; k0 < K; k0 += 64) {
#pragma unroll
    for (int j = 0; j < 4; ++j) {
      async16(A + (size_t)(m0 + rowS[j]) * K + k0 + colS[j], (char*)sA + offS[j]);
      async16(Bt + (size_t)(n0 + rowS[j]) * K + k0 + colS[j], (char*)sB + offS[j]);
    }
    __syncthreads();   // drains vmcnt -> staged data visible
#pragma unroll
    for (int kk = 0; kk < 2; ++kk) {
      bf16x8 af[4], bg[4];
      const int kb = (kk << 2) + q;
#pragma unroll
      for (int mt = 0; mt < 4; ++mt) {
        int m = wm + (mt << 4) + r;
        int cb = kb ^ (m & 7);
        af[mt] = *(const bf16x8*)(sA + m * 64 + cb * 8);
      }
#pragma unroll
      for (int nt = 0; nt < 4; ++nt) {
        int n = wn + (nt << 4) + r;
        int cb = kb ^ (n & 7);
        bg[nt] = *(const bf16x8*)(sB + n * 64 + cb * 8);
      }
#pragma unroll
      for (int mt = 0; mt < 4; ++mt)
#pragma unroll
        for (int nt = 0; nt < 4; ++nt)
          acc[mt][nt] = __builtin_amdgcn_mfma_f32_16x16x32_bf16(af[mt], bg[nt], acc[mt][nt], 0, 0, 0);
    }
    __syncthreads();
  }
}

// GEMM1: X = xs_bf [N_ROWS,K_IN] @ Wt_bf^T -> X_bf [N_ROWS,F_DIM]
__global__ __launch_bounds__(256, 3) void gemm_xw(const u16* __restrict__ A,
                                                  const u16* __restrict__ Bt,
                                                  u16* __restrict__ X) {
  __shared__ __align__(16) u16 sA[128 * 64];
  __shared__ __align__(16) u16 sB[128 * 64];
  const int tid = threadIdx.x;
  const int m0 = blockIdx.y << 7;
  const int n0 = blockIdx.x << 7;
  f32x4 acc[4][4];
  gemm_tile<K_IN>(A, Bt, m0, n0, sA, sB, tid, acc);

  const int lane = tid & 63;
  const int q = lane >> 4;
  const int r = lane & 15;
  const int wave = tid >> 6;
  const int wm = (wave >> 1) << 6;
  const int wn = (wave & 1) << 6;
#pragma unroll
  for (int mt = 0; mt < 4; ++mt) {
#pragma unroll
    for (int nt = 0; nt < 4; ++nt) {
      int row = m0 + wm + (mt << 4) + (q << 2);
      int col = n0 + wn + (nt << 4) + r;
#pragma unroll
      for (int e = 0; e < 4; ++e)
        X[(size_t)(row + e) * F_DIM + col] = f2bf(acc[mt][nt][e]);
    }
  }
}

// GEMM2 (triangular) + fused RBF epilogue + reduction
__global__ __launch_bounds__(256, 3) void gemm_kern(const u16* __restrict__ X,
                                                    const float* __restrict__ sq,
                                                    const float* __restrict__ beta,
                                                    float* __restrict__ out) {
  __shared__ __align__(16) u16 sA[128 * 64];
  __shared__ __align__(16) u16 sB[128 * 64];
  const int tid = threadIdx.x;
  int bid = blockIdx.x;
  int ib = 0;
  while (bid >= 32 - ib) { bid -= 32 - ib; ++ib; }
  const int jb = ib + bid;
  const int m0 = ib << 7;
  const int n0 = jb << 7;

  f32x4 acc[4][4];
  gemm_tile<F_DIM>(X, X, m0, n0, sA, sB, tid, acc);

  const int lane = tid & 63;
  const int q = lane >> 4;
  const int r = lane & 15;
  const int wave = tid >> 6;
  const int wm = (wave >> 1) << 6;
  const int wn = (wave & 1) << 6;

  float sqj[4], bj[4];
#pragma unroll
  for (int nt = 0; nt < 4; ++nt) {
    int j = n0 + wn + (nt << 4) + r;
    sqj[nt] = sq[j];
    bj[nt] = beta[j];
  }
  float local = 0.f;
#pragma unroll
  for (int mt = 0; mt < 4; ++mt) {
#pragma unroll
    for (int e = 0; e < 4; ++e) {
      int i = m0 + wm + (mt << 4) + (q << 2) + e;
      float sqi = sq[i];
      float bi = beta[i];
#pragma unroll
      for (int nt = 0; nt < 4; ++nt) {
        float d2 = fmaxf(sqi + sqj[nt] - 2.f * acc[mt][nt][e], 0.f);
        local += bi * bj[nt] * __expf(-GAMMA * d2);
      }
    }
  }
  // diag blocks once (x0.5 for the 0.5*quad form), off-diag twice (x1.0)
  local *= (ib == jb) ? 0.5f : 1.0f;
#pragma unroll
  for (int off = 32; off; off >>= 1) local += __shfl_down(local, off);
  if (lane == 0) atomicAdd(out, local);
}

// ---------------- launch ----------------

extern "C" void kernel_launch(void* const* d_in, const int* in_sizes, int n_in,
                              void* d_out, int out_size, void* d_ws, size_t ws_size,
                              hipStream_t stream) {
  const float* xs = (const float*)d_in[0];
  const float* W = (const float*)d_in[1];
  const int* ys = (const int*)d_in[2];
  const float* alphas = (const float*)d_in[3];
  float* out = (float*)d_out;

  char* ws = (char*)d_ws;
  u16* xs_bf = (u16*)ws;                      //  64 MB: [4096, 8192] bf16
  u16* Wt_bf = (u16*)(ws + 67108864);         //  32 MB: [2048, 8192] bf16
  u16* X_bf  = (u16*)(ws + 100663296);        //  16 MB: [4096, 2048] bf16
  float* sq   = (float*)(ws + 117440512);     //  16 KB
  float* beta = (float*)(ws + 117456896);     //  16 KB

  convert_xs<<<8192, 256, 0, stream>>>((const float4*)xs, (ushort4*)xs_bf,
                                       (N_ROWS * K_IN) / 4);
  dim3 tb(32, 8);
  dim3 tg(F_DIM / 32, K_IN / 32);
  transpose_w<<<tg, tb, 0, stream>>>(W, Wt_bf);
  prep<<<1, 1024, 0, stream>>>(alphas, ys, beta, out);

  dim3 g1(F_DIM / 128, N_ROWS / 128);
  gemm_xw<<<g1, 256, 0, stream>>>(xs_bf, Wt_bf, X_bf);
  row_sq<<<N_ROWS / 4, 256, 0, stream>>>(X_bf, sq);
  gemm_kern<<<528, 256, 0, stream>>>(X_bf, sq, beta, out);
}

// Round 3
// 366.916 us; speedup vs baseline: 1.3283x; 1.3283x over previous
//
#include <hip/hip_runtime.h>
#include <hip/hip_bf16.h>

#define N_ROWS 4096
#define K_IN   8192
#define F_DIM  2048
#define GAMMA  (1.0f / 2048.0f)

typedef unsigned short u16;
typedef unsigned int   u32;
typedef unsigned char  u8;
typedef __attribute__((ext_vector_type(4))) int   i32x4;
typedef __attribute__((ext_vector_type(8))) int   i32x8;
typedef __attribute__((ext_vector_type(4))) float f32x4;
typedef __attribute__((ext_vector_type(2))) float f32x2;

// pack 4 floats -> 4 fp8 e4m3 bytes (hw RNE conversion)
__device__ __forceinline__ u32 pk4_fp8(float a, float b, float c, float d) {
  u32 u = 0;
  u = __builtin_amdgcn_cvt_pk_fp8_f32(a, b, u, false);
  u = __builtin_amdgcn_cvt_pk_fp8_f32(c, d, u, true);
  return u;
}
__device__ __forceinline__ u8 f8(float v) {
  return (u8)(__builtin_amdgcn_cvt_pk_fp8_f32(v, v, 0, false) & 0xff);
}

__device__ __forceinline__ void async16(const void* g, void* l) {
  __builtin_amdgcn_global_load_lds(
      (const __attribute__((address_space(1))) void*)g,
      (__attribute__((address_space(3))) void*)l, 16, 0, 0);
}

// ---------------- conversion kernels ----------------

// xs fp32 -> fp8 e4m3 (unit scale; xs ~ N(0,1) fits e4m3 normal range)
__global__ void convert_xs(const float4* __restrict__ in, u32* __restrict__ out, int n4) {
  int base = blockIdx.x * (blockDim.x * 4) + threadIdx.x;
#pragma unroll
  for (int k = 0; k < 4; ++k) {
    int i = base + k * 256;
    if (i < n4) {
      float4 v = in[i];
      out[i] = pk4_fp8(v.x, v.y, v.z, v.w);
    }
  }
}

// W [K_IN, F_DIM] fp32 -> Wt [F_DIM, K_IN] fp8, scaled x64 (w~0.011 would be
// subnormal in e4m3; the 2^-6 is folded back via the MFMA B-scale operand)
__global__ void transpose_w(const float* __restrict__ W, u8* __restrict__ Wt) {
  __shared__ float tile[128][33];
  int k0 = blockIdx.x * 128;     // over K_IN/128
  int f0 = blockIdx.y * 32;      // over F_DIM/32
  int tx = threadIdx.x, ty = threadIdx.y;   // (32, 8)
#pragma unroll
  for (int kk = 0; kk < 16; ++kk) {
    int k = kk * 8 + ty;
    tile[k][tx] = 64.0f * W[(size_t)(k0 + k) * F_DIM + f0 + tx];
  }
  __syncthreads();
#pragma unroll
  for (int ff = 0; ff < 4; ++ff) {
    int f = ff * 8 + ty;
    int kk = tx * 4;
    u32 p = pk4_fp8(tile[kk][f], tile[kk + 1][f], tile[kk + 2][f], tile[kk + 3][f]);
    *(u32*)(Wt + (size_t)(f0 + f) * K_IN + k0 + kk) = p;
  }
}

// beta[i] = alpha[i] * (2*y[i]-1); out[0] = -sum(alpha)
__global__ void prep(const float* __restrict__ alphas, const int* __restrict__ ys,
                     float* __restrict__ beta, float* __restrict__ out) {
  __shared__ float red[1024];
  int t = threadIdx.x;
  float s = 0.f;
  for (int i = t; i < N_ROWS; i += 1024) {
    float a = alphas[i];
    beta[i] = a * (float)(2 * ys[i] - 1);
    s += a;
  }
  red[t] = s;
  __syncthreads();
  for (int off = 512; off; off >>= 1) {
    if (t < off) red[t] += red[t + off];
    __syncthreads();
  }
  if (t == 0) out[0] = -red[0];
}

// sq[i] = sum_f dequant(X_fp8[i][f])^2 — from the SAME quantized X the gram
// MFMA consumes, so d2_ii == 0 exactly and K_ii == 1 (diagonal term exact).
__global__ void row_sq(const u32* __restrict__ X, float* __restrict__ sq) {
  int wave = threadIdx.x >> 6, lane = threadIdx.x & 63;
  int row = blockIdx.x * 4 + wave;
  const uint4* xr = (const uint4*)(X + (size_t)row * (F_DIM / 4));
  float s = 0.f;
#pragma unroll
  for (int it = 0; it < 2; ++it) {
    uint4 v = xr[lane + it * 64];
    u32 w[4] = {v.x, v.y, v.z, v.w};
#pragma unroll
    for (int p = 0; p < 4; ++p) {
      f32x2 lo = __builtin_amdgcn_cvt_pk_f32_fp8(w[p], false);
      f32x2 hi = __builtin_amdgcn_cvt_pk_f32_fp8(w[p], true);
      s += lo[0] * lo[0] + lo[1] * lo[1] + hi[0] * hi[0] + hi[1] * hi[1];
    }
  }
#pragma unroll
  for (int off = 32; off; off >>= 1) s += __shfl_down(s, off);
  if (lane == 0) sq[row] = s;
}

// ------- MX-fp8 GEMM core: 128x128 tile, BK=128, 16x16x128 f8f6f4 -------
// LDS rows are 128 B (128 fp8); same xor-8 16B-block swizzle that measured
// SQ_LDS_BANK_CONFLICT == 0 in the bf16 version (identical address structure).

template <int K>
__device__ __forceinline__ void gemm_tile_f8(const u8* __restrict__ A, const u8* __restrict__ Bt,
                                             int m0, int n0, u8* sA, u8* sB, int tid,
                                             int sclA, int sclB, f32x4 acc[4][4]) {
  const int lane = tid & 63;
  const int q = lane >> 4;
  const int r = lane & 15;
  const int wave = tid >> 6;
  const int wm = (wave >> 1) << 6;
  const int wn = (wave & 1) << 6;

  const f32x4 zero = {0.f, 0.f, 0.f, 0.f};
#pragma unroll
  for (int mt = 0; mt < 4; ++mt)
#pragma unroll
    for (int nt = 0; nt < 4; ++nt) acc[mt][nt] = zero;

  int rowS[4], colS[4], offS[4];
#pragma unroll
  for (int j = 0; j < 4; ++j) {
    int o = tid * 16 + j * 4096;   // byte offset inside 16KB tile
    int row = o >> 7;              // 128 B per LDS row (128 fp8)
    int cb = (o >> 4) & 7;         // 16B block within row
    rowS[j] = row;
    colS[j] = ((cb ^ (row & 7)) << 4);  // global byte col (xor swizzle)
    offS[j] = o;
  }

  for (int k0 = 0; k0 < K; k0 += 128) {
#pragma unroll
    for (int j = 0; j < 4; ++j) {
      async16(A + (size_t)(m0 + rowS[j]) * K + k0 + colS[j], sA + offS[j]);
      async16(Bt + (size_t)(n0 + rowS[j]) * K + k0 + colS[j], sB + offS[j]);
    }
    __syncthreads();   // drains vmcnt -> staged data visible

    // A-frag 16x16x128: lane(16g+r) holds row r, k in [32g, 32g+32)
    i32x8 af[4], bg[4];
#pragma unroll
    for (int mt = 0; mt < 4; ++mt) {
      int m = wm + (mt << 4) + r;
      i32x4 lo = *(const i32x4*)(sA + m * 128 + ((((q << 1) | 0) ^ (m & 7)) << 4));
      i32x4 hi = *(const i32x4*)(sA + m * 128 + ((((q << 1) | 1) ^ (m & 7)) << 4));
      i32x8 f = {lo[0], lo[1], lo[2], lo[3], hi[0], hi[1], hi[2], hi[3]};
      af[mt] = f;
    }
#pragma unroll
    for (int nt = 0; nt < 4; ++nt) {
      int n = wn + (nt << 4) + r;
      i32x4 lo = *(const i32x4*)(sB + n * 128 + ((((q << 1) | 0) ^ (n & 7)) << 4));
      i32x4 hi = *(const i32x4*)(sB + n * 128 + ((((q << 1) | 1) ^ (n & 7)) << 4));
      i32x8 f = {lo[0], lo[1], lo[2], lo[3], hi[0], hi[1], hi[2], hi[3]};
      bg[nt] = f;
    }
#pragma unroll
    for (int mt = 0; mt < 4; ++mt)
#pragma unroll
      for (int nt = 0; nt < 4; ++nt)
        acc[mt][nt] = __builtin_amdgcn_mfma_scale_f32_16x16x128_f8f6f4(
            af[mt], bg[nt], acc[mt][nt], 0, 0, 0, sclA, 0, sclB);
    __syncthreads();
  }
}

// GEMM1: X = xs_f8 [N_ROWS,K_IN] @ Wt_f8^T -> X_f8 [N_ROWS,F_DIM]
// B-scale = 121 (e8m0 2^-6) undoes the x64 in transpose_w.
__global__ __launch_bounds__(256, 3) void gemm_xw(const u8* __restrict__ A,
                                                  const u8* __restrict__ Bt,
                                                  u8* __restrict__ X) {
  __shared__ __align__(16) u8 sA[128 * 128];
  __shared__ __align__(16) u8 sB[128 * 128];
  const int tid = threadIdx.x;
  const int m0 = blockIdx.y << 7;
  const int n0 = blockIdx.x << 7;
  f32x4 acc[4][4];
  gemm_tile_f8<K_IN>(A, Bt, m0, n0, sA, sB, tid, 127, 121, acc);

  const int lane = tid & 63;
  const int q = lane >> 4;
  const int r = lane & 15;
  const int wave = tid >> 6;
  const int wm = (wave >> 1) << 6;
  const int wn = (wave & 1) << 6;
#pragma unroll
  for (int mt = 0; mt < 4; ++mt) {
#pragma unroll
    for (int nt = 0; nt < 4; ++nt) {
      int row = m0 + wm + (mt << 4) + (q << 2);
      int col = n0 + wn + (nt << 4) + r;
#pragma unroll
      for (int e = 0; e < 4; ++e)
        X[(size_t)(row + e) * F_DIM + col] = f8(acc[mt][nt][e]);
    }
  }
}

// GEMM2 (triangular) + fused RBF epilogue + reduction
__global__ __launch_bounds__(256, 3) void gemm_kern(const u8* __restrict__ X,
                                                    const float* __restrict__ sq,
                                                    const float* __restrict__ beta,
                                                    float* __restrict__ out) {
  __shared__ __align__(16) u8 sA[128 * 128];
  __shared__ __align__(16) u8 sB[128 * 128];
  const int tid = threadIdx.x;
  int bid = blockIdx.x;
  int ib = 0;
  while (bid >= 32 - ib) { bid -= 32 - ib; ++ib; }
  const int jb = ib + bid;
  const int m0 = ib << 7;
  const int n0 = jb << 7;

  f32x4 acc[4][4];
  gemm_tile_f8<F_DIM>(X, X, m0, n0, sA, sB, tid, 127, 127, acc);

  const int lane = tid & 63;
  const int q = lane >> 4;
  const int r = lane & 15;
  const int wave = tid >> 6;
  const int wm = (wave >> 1) << 6;
  const int wn = (wave & 1) << 6;

  float sqj[4], bj[4];
#pragma unroll
  for (int nt = 0; nt < 4; ++nt) {
    int j = n0 + wn + (nt << 4) + r;
    sqj[nt] = sq[j];
    bj[nt] = beta[j];
  }
  float local = 0.f;
#pragma unroll
  for (int mt = 0; mt < 4; ++mt) {
#pragma unroll
    for (int e = 0; e < 4; ++e) {
      int i = m0 + wm + (mt << 4) + (q << 2) + e;
      float sqi = sq[i];
      float bi = beta[i];
#pragma unroll
      for (int nt = 0; nt < 4; ++nt) {
        float d2 = fmaxf(sqi + sqj[nt] - 2.f * acc[mt][nt][e], 0.f);
        local += bi * bj[nt] * __expf(-GAMMA * d2);
      }
    }
  }
  // diag blocks once (x0.5 for the 0.5*quad form), off-diag twice (x1.0)
  local *= (ib == jb) ? 0.5f : 1.0f;
#pragma unroll
  for (int off = 32; off; off >>= 1) local += __shfl_down(local, off);
  if (lane == 0) atomicAdd(out, local);
}

// ---------------- launch ----------------

extern "C" void kernel_launch(void* const* d_in, const int* in_sizes, int n_in,
                              void* d_out, int out_size, void* d_ws, size_t ws_size,
                              hipStream_t stream) {
  const float* xs = (const float*)d_in[0];
  const float* W = (const float*)d_in[1];
  const int* ys = (const int*)d_in[2];
  const float* alphas = (const float*)d_in[3];
  float* out = (float*)d_out;

  char* ws = (char*)d_ws;
  u8* xs_f8 = (u8*)ws;                        //  32 MB: [4096, 8192] fp8
  u8* Wt_f8 = (u8*)(ws + 33554432);           //  16 MB: [2048, 8192] fp8 (x64)
  u8* X_f8  = (u8*)(ws + 50331648);           //   8 MB: [4096, 2048] fp8
  float* sq   = (float*)(ws + 58720256);      //  16 KB
  float* beta = (float*)(ws + 58736640);      //  16 KB

  convert_xs<<<8192, 256, 0, stream>>>((const float4*)xs, (u32*)xs_f8,
                                       (N_ROWS * K_IN) / 4);
  dim3 tb(32, 8);
  dim3 tg(K_IN / 128, F_DIM / 32);
  transpose_w<<<tg, tb, 0, stream>>>(W, Wt_f8);
  prep<<<1, 1024, 0, stream>>>(alphas, ys, beta, out);

  dim3 g1(F_DIM / 128, N_ROWS / 128);
  gemm_xw<<<g1, 256, 0, stream>>>(xs_f8, Wt_f8, X_f8);
  row_sq<<<N_ROWS / 4, 256, 0, stream>>>((const u32*)X_f8, sq);
  gemm_kern<<<528, 256, 0, stream>>>(X_f8, sq, beta, out);
}